// Round 14
// baseline (441.801 us; speedup 1.0000x reference)
//
#include <hip/hip_runtime.h>
#include <hip/hip_bf16.h>

#define H 256

typedef _Float16 f16x8 __attribute__((ext_vector_type(8)));
typedef float    f32x4 __attribute__((ext_vector_type(4)));

// ---------------------------------------------------------------- K0: pack weights
// aW1F fp16 fragment-ordered: chunk e8 = ((nt*8+kk)*64+l):
//   j = nt*16 + (l&15), k = kk*32 + (l>>4)*8 + e  -> aW1[k*128+j]
__global__ __launch_bounds__(256) void k0_pack(
    const float* __restrict__ aW1, const float* __restrict__ gW1,
    const float* __restrict__ gW2,
    _Float16* __restrict__ aW1F, float* __restrict__ gW1P, float* __restrict__ gW2P)
{
    int idx = blockIdx.x * 256 + threadIdx.x;
    int stride = gridDim.x * 256;
    for (int e8 = idx; e8 < 4096; e8 += stride) {
        int l = e8 & 63, kknt = e8 >> 6;
        int kk = kknt & 7, nt = kknt >> 3;
        int j = nt*16 + (l & 15);
        int kbase = kk*32 + (l >> 4)*8;
        f16x8 v;
        #pragma unroll
        for (int e = 0; e < 8; ++e) v[e] = (_Float16)aW1[(kbase + e)*128 + j];
        *reinterpret_cast<f16x8*>(aW1F + e8*8) = v;
    }
    for (int e = idx; e < 64*256*4; e += stride) {
        int s = e & 3, j = (e >> 2) & 255, kq = e >> 10;
        gW1P[e] = gW1[(kq*4+s)*256 + j];
    }
    for (int e = idx; e < 64*128*4; e += stride) {
        int s = e & 3, j = (e >> 2) & 127, kq = e >> 9;
        gW2P[e] = gW2[(kq*4+s)*128 + j];
    }
}

// ---------------------------------------------------------------- K1: partial logits, register-only.
// No LDS, no barriers. Every wave covers ALL 64 rows of its tile; wave w computes
// the 32-hidden-col partial sum and writes lgP[row*4 + w]. k2 sums the quartet.
__global__ __launch_bounds__(256) void k1_logits(
    const float* __restrict__ emb, const _Float16* __restrict__ aW1F,
    const float* __restrict__ ab1, const float* __restrict__ aW2,
    float* __restrict__ lgP, int N, int ntiles)
{
    const int t = threadIdx.x, w = t >> 6, l = t & 63;
    const f32x4 zero = {0.f, 0.f, 0.f, 0.f};

    // persistent B-fragments: wave w owns hidden cols [32w, 32w+32)
    f16x8 bf[2][8];
    #pragma unroll
    for (int nt2 = 0; nt2 < 2; ++nt2)
        #pragma unroll
        for (int kk = 0; kk < 8; ++kk)
            bf[nt2][kk] = *reinterpret_cast<const f16x8*>(
                aW1F + (size_t)(((2*w + nt2)*8 + kk)*64 + l)*8);

    float b1v[2], w2v[2];
    #pragma unroll
    for (int nt2 = 0; nt2 < 2; ++nt2) {
        int j = 32*w + nt2*16 + (l & 15);
        b1v[nt2] = ab1[j];
        w2v[nt2] = aW2[j];
    }

    for (int tile = blockIdx.x; tile < ntiles; tile += gridDim.x) {
        long base = (long)tile * 64;
        #pragma unroll
        for (int rt = 0; rt < 4; ++rt) {
            long row  = base + rt*16 + (l & 15);
            long rowc = row < N ? row : (long)N - 1;   // clamp loads; writes guarded
            const float* rp = emb + rowc*H + (l >> 4)*8;

            f32x4 a20 = zero, a21 = zero;
            #pragma unroll
            for (int kk = 0; kk < 8; ++kk) {
                float4 x0 = *reinterpret_cast<const float4*>(rp + kk*32);
                float4 x1 = *reinterpret_cast<const float4*>(rp + kk*32 + 4);
                f16x8 af;
                af[0]=(_Float16)x0.x; af[1]=(_Float16)x0.y; af[2]=(_Float16)x0.z; af[3]=(_Float16)x0.w;
                af[4]=(_Float16)x1.x; af[5]=(_Float16)x1.y; af[6]=(_Float16)x1.z; af[7]=(_Float16)x1.w;
                a20 = __builtin_amdgcn_mfma_f32_16x16x32_f16(af, bf[0][kk], a20, 0, 0, 0);
                a21 = __builtin_amdgcn_mfma_f32_16x16x32_f16(af, bf[1][kk], a21, 0, 0, 0);
            }

            // bias+relu+aW2 partial dot over this wave's 32 cols; reduce 16 lanes
            #pragma unroll
            for (int r = 0; r < 4; ++r) {
                float h0 = a20[r] + b1v[0]; h0 = h0 > 0.f ? h0 : 0.f;
                float h1 = a21[r] + b1v[1]; h1 = h1 > 0.f ? h1 : 0.f;
                float p = h0*w2v[0] + h1*w2v[1];
                p += __shfl_xor(p, 1, 64);
                p += __shfl_xor(p, 2, 64);
                p += __shfl_xor(p, 4, 64);
                p += __shfl_xor(p, 8, 64);
                if ((l & 15) == 0) {
                    long orow = base + rt*16 + (l >> 4)*4 + r;   // C row=(lane>>4)*4+reg
                    if (orow < N) lgP[orow*4 + w] = p;
                }
            }
        }
    }
}

// ---------------------------------------------------------------- K2: segment softmax + weighted pool
// One block per molecule (R1-proven streaming). Logit = sum of 4 partials + bias.
__global__ __launch_bounds__(256) void k2_pool(
    const float* __restrict__ emb, const int* __restrict__ batch,
    const float* __restrict__ lgP, const float* __restrict__ ab2,
    float* __restrict__ mol, int N)
{
    int m = blockIdx.x;
    int t = threadIdx.x;
    const float bo = ab2[0];
    const float4* lg4 = reinterpret_cast<const float4*>(lgP);

    // segment bounds via binary search (batch sorted ascending)
    int lo = 0, hi = N;
    while (lo < hi) { int mid = (lo + hi) >> 1; if (batch[mid] < m) lo = mid + 1; else hi = mid; }
    int start = lo;
    hi = N;
    while (lo < hi) { int mid = (lo + hi) >> 1; if (batch[mid] < m + 1) lo = mid + 1; else hi = mid; }
    int end = lo;

    if (start >= end) { mol[(long)m*H + t] = 0.f; return; }

    __shared__ float red[8];
    __shared__ float wl[1024];

    // max
    float mx = -INFINITY;
    for (int i = start + t; i < end; i += 256) {
        float4 v = lg4[i];
        mx = fmaxf(mx, (v.x + v.y) + (v.z + v.w) + bo);
    }
    #pragma unroll
    for (int off = 32; off >= 1; off >>= 1) mx = fmaxf(mx, __shfl_xor(mx, off, 64));
    if ((t & 63) == 0) red[t >> 6] = mx;
    __syncthreads();
    mx = fmaxf(fmaxf(red[0], red[1]), fmaxf(red[2], red[3]));
    __syncthreads();

    // denom
    float s = 0.f;
    for (int i = start + t; i < end; i += 256) {
        float4 v = lg4[i];
        s += __expf((v.x + v.y) + (v.z + v.w) + bo - mx);
    }
    #pragma unroll
    for (int off = 32; off >= 1; off >>= 1) s += __shfl_xor(s, off, 64);
    if ((t & 63) == 0) red[t >> 6] = s;
    __syncthreads();
    s = red[0] + red[1] + red[2] + red[3];
    float inv = 1.0f / s;

    // weighted sum; thread t owns embedding dim t
    float acc = 0.f;
    for (int c = start; c < end; c += 1024) {
        int cnt = min(1024, end - c);
        __syncthreads();
        for (int ii = t; ii < cnt; ii += 256) {
            float4 v = lg4[c + ii];
            wl[ii] = __expf((v.x + v.y) + (v.z + v.w) + bo - mx) * inv;
        }
        __syncthreads();
        #pragma unroll 4
        for (int ii = 0; ii < cnt; ++ii) acc += wl[ii] * emb[(long)(c + ii)*H + t];
    }
    mol[(long)m*H + t] = acc;
}

// ---------------------------------------------------------------- K3: molecule MLP -> out[M]
__global__ __launch_bounds__(256) void k3_mlp(
    const float* __restrict__ mol, const float* __restrict__ gW1P,
    const float* __restrict__ gb1, const float* __restrict__ gW2P,
    const float* __restrict__ gb2, const float* __restrict__ gW3,
    const float* __restrict__ gb3, float* __restrict__ out, int M)
{
    __shared__ __align__(16) float mt[32 * 256];
    __shared__ __align__(16) float g1[32 * 256];
    __shared__ float tmp[4][16];
    int t = threadIdx.x;
    int blk = blockIdx.x;

    #pragma unroll
    for (int i = 0; i < 8; ++i) {
        int f = t + i*256;
        long gidx = (long)blk*2048 + f;
        float4 v = make_float4(0.f,0.f,0.f,0.f);
        if (gidx < (long)M*64) v = reinterpret_cast<const float4*>(mol)[gidx];
        reinterpret_cast<float4*>(mt)[f] = v;
    }
    __syncthreads();

    int j = t & 127, mh = t >> 7;

    float a0[16], a1[16];
    #pragma unroll
    for (int m = 0; m < 16; ++m) { a0[m] = 0.f; a1[m] = 0.f; }
    for (int kq = 0; kq < 64; ++kq) {
        float4 w0 = reinterpret_cast<const float4*>(gW1P)[kq*256 + j];
        float4 w1 = reinterpret_cast<const float4*>(gW1P)[kq*256 + j + 128];
        #pragma unroll
        for (int m = 0; m < 16; ++m) {
            float4 e = *reinterpret_cast<const float4*>(&mt[(mh*16 + m)*256 + kq*4]);
            a0[m] += e.x*w0.x + e.y*w0.y + e.z*w0.z + e.w*w0.w;
            a1[m] += e.x*w1.x + e.y*w1.y + e.z*w1.z + e.w*w1.w;
        }
    }
    {
        float b0 = gb1[j], b1 = gb1[j + 128];
        #pragma unroll
        for (int m = 0; m < 16; ++m) {
            float v0 = a0[m] + b0; v0 = v0 > 0.f ? v0 : 0.f;
            float v1 = a1[m] + b1; v1 = v1 > 0.f ? v1 : 0.f;
            g1[(mh*16 + m)*256 + j]       = v0;
            g1[(mh*16 + m)*256 + j + 128] = v1;
        }
    }
    __syncthreads();

    float a2[16];
    #pragma unroll
    for (int m = 0; m < 16; ++m) a2[m] = 0.f;
    for (int kq = 0; kq < 64; ++kq) {
        float4 w = reinterpret_cast<const float4*>(gW2P)[kq*128 + j];
        #pragma unroll
        for (int m = 0; m < 16; ++m) {
            float4 e = *reinterpret_cast<const float4*>(&g1[(mh*16 + m)*256 + kq*4]);
            a2[m] += e.x*w.x + e.y*w.y + e.z*w.z + e.w*w.w;
        }
    }

    float b2 = gb2[j], w3 = gW3[j];
    float p[16];
    #pragma unroll
    for (int m = 0; m < 16; ++m) {
        float v = a2[m] + b2; v = v > 0.f ? v : 0.f;
        p[m] = v * w3;
    }
    #pragma unroll
    for (int off = 32; off >= 1; off >>= 1) {
        #pragma unroll
        for (int m = 0; m < 16; ++m) p[m] += __shfl_xor(p[m], off, 64);
    }
    int wid = t >> 6;
    if ((t & 63) == 0) {
        #pragma unroll
        for (int m = 0; m < 16; ++m) tmp[wid][m] = p[m];
    }
    __syncthreads();
    if (t < 32) {
        int om = blk*32 + t;
        if (om < M) out[om] = tmp[(t >> 4)*2][t & 15] + tmp[(t >> 4)*2 + 1][t & 15] + gb3[0];
    }
}

// ---------------------------------------------------------------- launch
extern "C" void kernel_launch(void* const* d_in, const int* in_sizes, int n_in,
                              void* d_out, int out_size, void* d_ws, size_t ws_size,
                              hipStream_t stream) {
    const float* emb  = (const float*)d_in[0];
    const int*   batch= (const int*)d_in[1];
    const float* aW1  = (const float*)d_in[3];
    const float* ab1  = (const float*)d_in[4];
    const float* aW2  = (const float*)d_in[5];
    const float* ab2  = (const float*)d_in[6];
    const float* gW1  = (const float*)d_in[7];
    const float* gb1  = (const float*)d_in[8];
    const float* gW2  = (const float*)d_in[9];
    const float* gb2  = (const float*)d_in[10];
    const float* gW3  = (const float*)d_in[11];
    const float* gb3  = (const float*)d_in[12];
    float* outp = (float*)d_out;

    int N = in_sizes[0] / H;
    int M = out_size;

    char* ws = (char*)d_ws;
    size_t off = 0;
    float*     lgP    = (float*)(ws + off);    off += (8u<<20);   // N*4 floats
    float*     mol    = (float*)(ws + off);    off += (8u<<20);
    _Float16*  aW1F   = (_Float16*)(ws + off); off += 65536;
    float*     gW1P   = (float*)(ws + off);    off += 262144;
    float*     gW2P   = (float*)(ws + off);    off += 131072;

    int ntiles = (N + 63) / 64;
    int g1 = ntiles < 2048 ? ntiles : 2048;

    k0_pack<<<64, 256, 0, stream>>>(aW1, gW1, gW2, aW1F, gW1P, gW2P);
    k1_logits<<<g1, 256, 0, stream>>>(emb, aW1F, ab1, aW2, lgP, N, ntiles);
    k2_pool<<<M, 256, 0, stream>>>(emb, batch, lgP, ab2, mol, N);
    k3_mlp<<<(M + 31)/32, 256, 0, stream>>>(mol, gW1P, gb1, gW2P, gb2, gW3, gb3, outp, M);
}